// Round 5
// baseline (1845.728 us; speedup 1.0000x reference)
//
#include <hip/hip_runtime.h>
#include <cstddef>
#include <cstdint>

// Problem constants
#define B_DIM   4
#define L_SEQ   2048
#define C_DIM   2048
#define OUT_DIM 768
#define NHEADS  32
#define HDIM    64
#define MBS_    16
#define NMINI   128
#define EPS_    1e-6f

typedef _Float16 half8 __attribute__((ext_vector_type(8)));
typedef float floatx4 __attribute__((ext_vector_type(4)));

__device__ __forceinline__ void glds16(const void* g, void* l) {
    __builtin_amdgcn_global_load_lds(
        (const __attribute__((address_space(1))) uint32_t*)g,
        (__attribute__((address_space(3))) uint32_t*)l, 16, 0, 0);
}

__device__ __forceinline__ void split8(const float4 a, const float4 b,
                                       half8& hi, half8& lo) {
    const float x[8] = {a.x, a.y, a.z, a.w, b.x, b.y, b.z, b.w};
#pragma unroll
    for (int e = 0; e < 8; e++) {
        const _Float16 h = (_Float16)x[e];
        hi[e] = h;
        lo[e] = (_Float16)(x[e] - (float)h);
    }
}

#define MFMA3(ACC, AH, AL, BH, BL)                                             \
    ACC = __builtin_amdgcn_mfma_f32_16x16x32_f16((AH), (BH), ACC, 0, 0, 0);    \
    ACC = __builtin_amdgcn_mfma_f32_16x16x32_f16((AH), (BL), ACC, 0, 0, 0);    \
    ACC = __builtin_amdgcn_mfma_f32_16x16x32_f16((AL), (BH), ACC, 0, 0, 0);

// ======================================================================
// MFMA GEMM, A = fp32 [M][2048] split on the fly; B = fp16 hi/lo [N][K].
// (unchanged — proven in R3/R4)
// ======================================================================
__global__ __launch_bounds__(256)
void gemm_af32(const float* __restrict__ A,
               const _Float16* __restrict__ Bhi, const _Float16* __restrict__ Blo,
               float* __restrict__ Cout, int mode, int doRope)
{
    __shared__ __align__(16) float    sA[4096];
    __shared__ __align__(16) _Float16 sBhi[4096];
    __shared__ __align__(16) _Float16 sBlo[4096];
    const int tid = threadIdx.x;
    const int m0 = blockIdx.y * 128, n0 = blockIdx.x * 128;
    const int K = 2048;

    size_t gA[4]; float* lA[4];
#pragma unroll
    for (int I = 0; I < 4; I++) {
        const int c = I * 256 + tid;
        const int row = c >> 3, seg = (c & 7) ^ (row & 7);
        gA[I] = (size_t)(m0 + row) * K + seg * 4;
        lA[I] = &sA[c * 4];
    }
    size_t gB[2]; _Float16 *lBh[2], *lBl[2];
#pragma unroll
    for (int I = 0; I < 2; I++) {
        const int c = I * 256 + tid;
        const int row = c >> 2, seg = (c & 3) ^ ((row >> 1) & 3);
        gB[I] = (size_t)(n0 + row) * K + seg * 8;
        lBh[I] = &sBhi[c * 8];
        lBl[I] = &sBlo[c * 8];
    }

    const int lane = tid & 63, quad = lane >> 4, lc = lane & 15;
    const int wv = tid >> 6, wm = wv & 1, wn = wv >> 1;
    int offA0[4], offA1[4], offB[4];
#pragma unroll
    for (int i = 0; i < 4; i++) {
        const int rA = wm * 64 + i * 16 + lc;
        offA0[i] = (rA * 8 + ((2 * quad)     ^ (rA & 7))) * 4;
        offA1[i] = (rA * 8 + ((2 * quad + 1) ^ (rA & 7))) * 4;
    }
#pragma unroll
    for (int j = 0; j < 4; j++) {
        const int rB = wn * 64 + j * 16 + lc;
        offB[j] = (rB * 4 + (quad ^ ((rB >> 1) & 3))) * 8;
    }

    floatx4 acc[4][4];
#pragma unroll
    for (int i = 0; i < 4; i++)
#pragma unroll
        for (int j = 0; j < 4; j++) acc[i][j] = (floatx4)0.0f;

    for (int k0 = 0; k0 < K; k0 += 32) {
        __syncthreads();
#pragma unroll
        for (int I = 0; I < 4; I++) glds16(A + gA[I] + k0, lA[I]);
#pragma unroll
        for (int I = 0; I < 2; I++) {
            glds16(Bhi + gB[I] + k0, lBh[I]);
            glds16(Blo + gB[I] + k0, lBl[I]);
        }
        __syncthreads();

        half8 ah[4], al[4], bh[4], bl[4];
#pragma unroll
        for (int i = 0; i < 4; i++) {
            const float4 va = *(const float4*)&sA[offA0[i]];
            const float4 vb = *(const float4*)&sA[offA1[i]];
            split8(va, vb, ah[i], al[i]);
        }
#pragma unroll
        for (int j = 0; j < 4; j++) {
            bh[j] = *(const half8*)&sBhi[offB[j]];
            bl[j] = *(const half8*)&sBlo[offB[j]];
        }
#pragma unroll
        for (int i = 0; i < 4; i++)
#pragma unroll
            for (int j = 0; j < 4; j++) {
                MFMA3(acc[i][j], ah[i], al[i], bh[j], bl[j]);
            }
    }

    float cs[4][4], sn[4][4];
    if (doRope) {
#pragma unroll
        for (int j = 0; j < 4; j++) {
            const int ii = ((j * 16 + lc) & 63) >> 1;
            const float invf = expf(-(float)ii * 0.28782313662425574f);
#pragma unroll
            for (int r = 0; r < 4; r++) {
                const float ang = (float)(quad * 4 + r) * invf;
                sincosf(ang, &sn[j][r], &cs[j][r]);
            }
        }
    }
    const int oddcol = lc & 1;
#pragma unroll
    for (int i = 0; i < 4; i++) {
#pragma unroll
        for (int j = 0; j < 4; j++) {
            floatx4 v = acc[i][j];
            if (doRope) {
#pragma unroll
                for (int r = 0; r < 4; r++) {
                    const float partner = __shfl_xor(v[r], 1);
                    v[r] = v[r] * cs[j][r] + partner * (oddcol ? sn[j][r] : -sn[j][r]);
                }
            }
            const int n = n0 + wn * 64 + j * 16 + lc;
            if (mode == 0) {
                const int h = (n >> 6) & 31, d = n & 63;
#pragma unroll
                for (int r = 0; r < 4; r++) {
                    const int m = m0 + wm * 64 + i * 16 + quad * 4 + r;
                    const int b = m >> 11, li = m & 2047;
                    Cout[((size_t)(b * 32 + h) * 2048 + li) * 64 + d] = v[r];
                }
            } else {
#pragma unroll
                for (int r = 0; r < 4; r++) {
                    const int m = m0 + wm * 64 + i * 16 + quad * 4 + r;
                    Cout[(size_t)m * OUT_DIM + n] = v[r];
                }
            }
        }
    }
}

// ======================================================================
// Weight transpose + split
// ======================================================================
__global__ __launch_bounds__(256)
void wtrans_kernel(const float* __restrict__ W, _Float16* __restrict__ BThi,
                   _Float16* __restrict__ BTlo, int Nw)
{
    __shared__ float tile[32][33];
    const int t = threadIdx.x, tx = t & 31, ty = t >> 5;
    const int n0 = blockIdx.x * 32, k0 = blockIdx.y * 32;
    const int K = 2048;
#pragma unroll
    for (int r = 0; r < 4; r++)
        tile[ty + r * 8][tx] = W[(size_t)(k0 + ty + r * 8) * Nw + n0 + tx];
    __syncthreads();
#pragma unroll
    for (int r = 0; r < 4; r++) {
        const float val = tile[tx][ty + r * 8];
        const _Float16 hh = (_Float16)val;
        const size_t o = (size_t)(n0 + ty + r * 8) * K + k0 + tx;
        BThi[o] = hh;
        BTlo[o] = (_Float16)(val - (float)hh);
    }
}

// ======================================================================
// ttt_lr sigmoid
// ======================================================================
__global__ __launch_bounds__(256)
void lr_kernel(const float* __restrict__ hidden, const float* __restrict__ wlr,
               const float* __restrict__ lr_bias, float* __restrict__ lrs)
{
    __shared__ float sRow[2048];
    __shared__ float sPart[32][9];
    const int m = blockIdx.x;
    const int t = threadIdx.x;
    const float* row = hidden + (size_t)m * C_DIM;
#pragma unroll
    for (int j = 0; j < 8; j++) sRow[t + j * 256] = row[t + j * 256];
    __syncthreads();
    const int h = t >> 3, p = t & 7;
    const float* w = wlr + (size_t)h * C_DIM;
    float s = 0.0f;
#pragma unroll 8
    for (int k = 0; k < 64; k++) {
        const int c = k * 32 + p * 4;
        const float4 a = *(const float4*)(sRow + c);
        const float4 b = *(const float4*)(w + c);
        s += a.x * b.x + a.y * b.y + a.z * b.z + a.w * b.w;
    }
    sPart[h][p] = s;
    __syncthreads();
    if (t < 32) {
        float v = 0.0f;
#pragma unroll
        for (int p2 = 0; p2 < 8; p2++) v += sPart[t][p2];
        v += lr_bias[t];
        const float sig = 1.0f / (1.0f + expf(-v));
        lrs[((size_t)(m >> 11) * NHEADS + t) * L_SEQ + (m & 2047)] = sig;
    }
}

// ======================================================================
// Single-wave MFMA TTT scan: one WAVE (64 thr) per (b,h). No barriers —
// all LDS exchanges are wave-synchronous (lgkmcnt only). Minibatch
// staging double-buffered via global_load_lds (drained by one vmcnt(0)
// per step). W1 state in registers (C/D layout) + LDS W1T for B-frags.
// Same split-fp16 3-pass algebra as R4 (validated).
// ======================================================================
__global__ __launch_bounds__(64, 1)
void scan_1wave(const float* __restrict__ XQ, const float* __restrict__ XK,
                float* __restrict__ XVo, const float* __restrict__ LRS,
                const float* __restrict__ W1i, const float* __restrict__ b1i,
                const float* __restrict__ lt, const float* __restrict__ lnw,
                const float* __restrict__ lnb)
{
    __shared__ __align__(16) float sXq[2][1024];   // [16][64] XOR-cell
    __shared__ __align__(16) float sXk[2][1024];
    __shared__ __align__(16) float sXv[2][1024];
    __shared__ __align__(16) float sW1T[4096];     // [n][k] cell-XOR (k>>2)^(n&15)
    __shared__ __align__(16) float sGt[64 * 36];   // gradT[n][j], j 16..35 pad
    __shared__ __align__(16) float sKt[64 * 36];   // Kt[d][j] = le[j]*Xk[j][d]
    __shared__ __align__(16) float sCf[16 * 36];   // -coeff[i][j]
    __shared__ __align__(16) float sB1[64];
    __shared__ __align__(16) float sEta[32];       // [16..31] stay zero

    const int t = threadIdx.x;          // one wave: lane == t
    const int q = t >> 4, lc = t & 15;
    const int bh = blockIdx.x, h = bh & 31;

    // glds staging source offsets (16B cells, XOR within row)
    int srcOff[4];
#pragma unroll
    for (int I = 0; I < 4; I++) {
        const int c = I * 64 + t;
        const int row = c >> 4, seg = (c & 15) ^ (row & 15);
        srcOff[I] = row * 64 + seg * 4;
    }

    // constants (per-lane registers)
    float tokR[4];
#pragma unroll
    for (int r = 0; r < 4; r++)
        tokR[r] = fmaxf(1.0f / (float)(4 * q + r + 1) + lt[4 * q + r], 0.0f);
    const float tok15 = fmaxf(1.0f / 16.0f + lt[15], 0.0f);
    float gamR[4], betR[4];
#pragma unroll
    for (int j = 0; j < 4; j++) {
        gamR[j] = lnw[h * 64 + 16 * j + lc];
        betR[j] = lnb[h * 64 + 16 * j + lc];
    }
    sB1[t] = b1i[h * 64 + t];
    if (t < 32) sEta[t] = 0.0f;
    for (int z = t; z < 1024; z += 64) {
        const int r = z >> 4, c = 16 + (z & 15);
        sGt[r * 36 + c] = 0.0f;
        sKt[r * 36 + c] = 0.0f;
    }
    for (int z = t; z < 256; z += 64) {
        const int r = z >> 4, c = 16 + (z & 15);
        sCf[r * 36 + c] = 0.0f;
    }

    // W1 state: w1s[w][t4][r] = W1T[16w+4q+r][16t4+lc] = W1[16t4+lc][16w+4q+r]
    float w1s[4][4][4];
#pragma unroll
    for (int w = 0; w < 4; w++)
#pragma unroll
        for (int t4 = 0; t4 < 4; t4++)
#pragma unroll
            for (int r = 0; r < 4; r++)
                w1s[w][t4][r] = W1i[h * 4096 + (16 * t4 + lc) * 64 + (16 * w + 4 * q + r)];
#pragma unroll
    for (int w = 0; w < 4; w++)
#pragma unroll
        for (int t4 = 0; t4 < 4; t4++)
#pragma unroll
            for (int r = 0; r < 4; r++) {
                const int nn = 16 * w + 4 * q + r, k = 16 * t4 + lc;
                sW1T[nn * 64 + ((((k >> 2) ^ (nn & 15)) << 2) | (k & 3))] = w1s[w][t4][r];
            }

    const size_t base = (size_t)bh * L_SEQ * HDIM;
    const float* xq_g = XQ + base;
    const float* xk_g = XK + base;
    float* xv_g = XVo + base;
    const float* lr_g = LRS + (size_t)bh * L_SEQ;

    // prefetch minibatch 0 into buf 0
#pragma unroll
    for (int I = 0; I < 4; I++) {
        glds16(xq_g + srcOff[I], &sXq[0][(I * 64 + t) * 4]);
        glds16(xk_g + srcOff[I], &sXk[0][(I * 64 + t) * 4]);
        glds16(xv_g + srcOff[I], &sXv[0][(I * 64 + t) * 4]);
    }
    float clr = lr_g[lc];

    for (int n = 0; n < NMINI; n++) {
        const int buf = n & 1, nb = buf ^ 1;
        __asm volatile("s_waitcnt vmcnt(0)" ::: "memory");   // current buf + clr ready

        if (t < 16) sEta[t] = clr * (1.0f / 64.0f);
        // issue next-minibatch prefetch (lands by next step's vmcnt(0))
        const int np = (n + 1) & (NMINI - 1);
        const size_t go = (size_t)np * 1024;
#pragma unroll
        for (int I = 0; I < 4; I++) {
            glds16(xq_g + go + srcOff[I], &sXq[nb][(I * 64 + t) * 4]);
            glds16(xk_g + go + srcOff[I], &sXk[nb][(I * 64 + t) * 4]);
            glds16(xv_g + go + srcOff[I], &sXv[nb][(I * 64 + t) * 4]);
        }
        const float nlr = lr_g[np * 16 + lc];
        __asm volatile("s_waitcnt lgkmcnt(0)" ::: "memory"); // sEta/sB1/sW1T visible

        float b1R[4];
#pragma unroll
        for (int j = 0; j < 4; j++) b1R[j] = sB1[16 * j + lc];
        const float etaLc = sEta[lc];
        const float leC = tok15 * etaLc;

        // build Kt[d][j] = le[j]*Xk[j][d]  (transpose via LDS, wave-sync)
#pragma unroll
        for (int i4 = 0; i4 < 4; i4++) {
            const int phys = q + 4 * i4;
            const float4 v = *(const float4*)&sXk[buf][lc * 64 + phys * 4];
            const int cb = 4 * (phys ^ lc);
            sKt[(cb + 0) * 36 + lc] = v.x * leC;
            sKt[(cb + 1) * 36 + lc] = v.y * leC;
            sKt[(cb + 2) * 36 + lc] = v.z * leC;
            sKt[(cb + 3) * 36 + lc] = v.w * leC;
        }

        // A-fragments Xq/Xk (rows = lc)
        half8 qh[2], ql[2], kh[2], kl[2];
#pragma unroll
        for (int f = 0; f < 2; f++) {
            const int ca = (8 * f + 2 * q) ^ lc, cb = (8 * f + 2 * q + 1) ^ lc;
            {
                const float4 u0 = *(const float4*)&sXq[buf][lc * 64 + ca * 4];
                const float4 u1 = *(const float4*)&sXq[buf][lc * 64 + cb * 4];
                split8(u0, u1, qh[f], ql[f]);
            }
            {
                const float4 u0 = *(const float4*)&sXk[buf][lc * 64 + ca * 4];
                const float4 u1 = *(const float4*)&sXk[buf][lc * 64 + cb * 4];
                split8(u0, u1, kh[f], kl[f]);
            }
        }

        // forward MFMAs: Attn + per-j-tile z1 / xq@W1
        floatx4 at = (floatx4)0.0f;
#pragma unroll
        for (int f = 0; f < 2; f++) { MFMA3(at, qh[f], ql[f], kh[f], kl[f]); }

        floatx4 z1a[4], zba[4];
#pragma unroll
        for (int j = 0; j < 4; j++) {
            z1a[j] = (floatx4)0.0f; zba[j] = (floatx4)0.0f;
#pragma unroll
            for (int f = 0; f < 2; f++) {
                const int ca = (8 * f + 2 * q) ^ lc, cb = (8 * f + 2 * q + 1) ^ lc;
                const int rw = 16 * j + lc;
                half8 wh, wl;
                const float4 u0 = *(const float4*)&sW1T[rw * 64 + ca * 4];
                const float4 u1 = *(const float4*)&sW1T[rw * 64 + cb * 4];
                split8(u0, u1, wh, wl);
                MFMA3(z1a[j], kh[f], kl[f], wh, wl);
                MFMA3(zba[j], qh[f], ql[f], wh, wl);
            }
        }

        // Z1 row stats (rows 4q+r live entirely in this quad's lanes)
        float zz[4][4], s1[4], s2[4];
#pragma unroll
        for (int r = 0; r < 4; r++) { s1[r] = 0.0f; s2[r] = 0.0f; }
#pragma unroll
        for (int j = 0; j < 4; j++)
#pragma unroll
            for (int r = 0; r < 4; r++) {
                zz[j][r] = z1a[j][r] + b1R[j];
                s1[r] += zz[j][r];
                s2[r] += zz[j][r] * zz[j][r];
            }
#pragma unroll
        for (int o = 1; o < 16; o <<= 1)
#pragma unroll
            for (int r = 0; r < 4; r++) { s1[r] += __shfl_xor(s1[r], o); s2[r] += __shfl_xor(s2[r], o); }
        float mu[4], rs[4];
#pragma unroll
        for (int r = 0; r < 4; r++) {
            mu[r] = s1[r] * (1.0f / 64.0f);
            rs[r] = rsqrtf(s2[r] * (1.0f / 64.0f) - mu[r] * mu[r] + EPS_);
        }

        // LN-L2 grad
        float gg[4][4], xh[4][4], g1[4], g2[4];
#pragma unroll
        for (int r = 0; r < 4; r++) { g1[r] = 0.0f; g2[r] = 0.0f; }
#pragma unroll
        for (int j = 0; j < 4; j++)
#pragma unroll
            for (int r = 0; r < 4; r++) {
                const int row = 4 * q + r, col = 16 * j + lc;
                const int ad = row * 64 + (((((col >> 2) ^ row) & 15) << 2) | (col & 3));
                xh[j][r] = (zz[j][r] - mu[r]) * rs[r];
                const float tgt = sXv[buf][ad] - sXk[buf][ad];
                gg[j][r] = (gamR[j] * xh[j][r] + betR[j] - tgt) * gamR[j];
                g1[r] += gg[j][r];
                g2[r] += gg[j][r] * xh[j][r];
            }
#pragma unroll
        for (int o = 1; o < 16; o <<= 1)
#pragma unroll
            for (int r = 0; r < 4; r++) { g1[r] += __shfl_xor(g1[r], o); g2[r] += __shfl_xor(g2[r], o); }
#pragma unroll
        for (int j = 0; j < 4; j++) {
            float4 g4;
#pragma unroll
            for (int r = 0; r < 4; r++) {
                const float gr = (64.0f * gg[j][r] - g1[r] - xh[j][r] * g2[r]) * rs[r] * (1.0f / 64.0f);
                ((float*)&g4)[r] = gr;
            }
            *(float4*)&sGt[(16 * j + lc) * 36 + 4 * q] = g4;   // gradT[n][row]
        }
        // coeff (C/D: i = 4q+r, j' = lc)
#pragma unroll
        for (int r = 0; r < 4; r++) {
            const int i = 4 * q + r;
            sCf[i * 36 + lc] = (lc <= i) ? -tokR[r] * etaLc * (at[r] + 1.0f) : 0.0f;
        }
        __asm volatile("s_waitcnt lgkmcnt(0)" ::: "memory"); // sGt/sCf/sKt visible

        // cf A-frag (K=32 with zero pad covers all 16 j')
        half8 cfh, cfl;
        {
            const float4 u0 = *(const float4*)&sCf[lc * 36 + 8 * q];
            const float4 u1 = *(const float4*)&sCf[lc * 36 + 8 * q + 4];
            split8(u0, u1, cfh, cfl);
        }
        // gradT frags (reused as B operand for zba and A operand for update)
        half8 gth[4], gtl[4];
#pragma unroll
        for (int j = 0; j < 4; j++) {
            const float4 u0 = *(const float4*)&sGt[(16 * j + lc) * 36 + 8 * q];
            const float4 u1 = *(const float4*)&sGt[(16 * j + lc) * 36 + 8 * q + 4];
            split8(u0, u1, gth[j], gtl[j]);
            MFMA3(zba[j], cfh, cfl, gth[j], gtl[j]);
        }
        // W1 update: w1s[w][t4] -= mfma(gradT[w], Kt[t4])
#pragma unroll
        for (int t4 = 0; t4 < 4; t4++) {
            half8 kth, ktl;
            const float4 u0 = *(const float4*)&sKt[(16 * t4 + lc) * 36 + 8 * q];
            const float4 u1 = *(const float4*)&sKt[(16 * t4 + lc) * 36 + 8 * q + 4];
            split8(u0, u1, kth, ktl);
#pragma unroll
            for (int w = 0; w < 4; w++) {
                floatx4 up = (floatx4)0.0f;
                MFMA3(up, gth[w], gtl[w], kth, ktl);
#pragma unroll
                for (int r = 0; r < 4; r++) w1s[w][t4][r] -= up[r];
            }
        }

        // Zbar stats
#pragma unroll
        for (int r = 0; r < 4; r++) { s1[r] = 0.0f; s2[r] = 0.0f; }
        float z2[4][4];
#pragma unroll
        for (int j = 0; j < 4; j++)
#pragma unroll
            for (int r = 0; r < 4; r++) {
                z2[j][r] = zba[j][r] + b1R[j];
                s1[r] += z2[j][r];
                s2[r] += z2[j][r] * z2[j][r];
            }
#pragma unroll
        for (int o = 1; o < 16; o <<= 1)
#pragma unroll
            for (int r = 0; r < 4; r++) { s1[r] += __shfl_xor(s1[r], o); s2[r] += __shfl_xor(s2[r], o); }
#pragma unroll
        for (int r = 0; r < 4; r++) {
            mu[r] = s1[r] * (1.0f / 64.0f);
            rs[r] = rsqrtf(s2[r] * (1.0f / 64.0f) - mu[r] * mu[r] + EPS_);
        }
        // out = xq + LN(Zbar)
#pragma unroll
        for (int j = 0; j < 4; j++)
#pragma unroll
            for (int r = 0; r < 4; r++) {
                const int row = 4 * q + r, col = 16 * j + lc;
                const int ad = row * 64 + (((((col >> 2) ^ row) & 15) << 2) | (col & 3));
                xv_g[n * 1024 + row * 64 + col] =
                    sXq[buf][ad] + gamR[j] * ((z2[j][r] - mu[r]) * rs[r]) + betR[j];
            }

        // b1 update: b1[n] -= tok15 * sum_j' eta[j']*grad[j'][n]
        {
            const float4 e0 = *(const float4*)&sEta[8 * q];
            const float4 e1 = *(const float4*)&sEta[8 * q + 4];
            const float ev[8] = {e0.x, e0.y, e0.z, e0.w, e1.x, e1.y, e1.z, e1.w};
#pragma unroll
            for (int w = 0; w < 4; w++) {
                float p = 0.0f;
#pragma unroll
                for (int jj = 0; jj < 8; jj++)
                    p += ((float)gth[w][jj] + (float)gtl[w][jj]) * ev[jj];
                p += __shfl_xor(p, 16);
                if (q == 0) sB1[16 * w + lc] -= tok15 * p;
            }
        }

        // W1T writeback for next step's B-frags
#pragma unroll
        for (int w = 0; w < 4; w++)
#pragma unroll
            for (int t4 = 0; t4 < 4; t4++)
#pragma unroll
                for (int r = 0; r < 4; r++) {
                    const int nn = 16 * w + 4 * q + r, k = 16 * t4 + lc;
                    sW1T[nn * 64 + ((((k >> 2) ^ (nn & 15)) << 2) | (k & 3))] = w1s[w][t4][r];
                }
        clr = nlr;
    }
}

// ======================================================================
// post-norm: gather (B,NH,L,HD) -> LN over C=2048 -> fp32 (B,L,C)
// ======================================================================
__global__ __launch_bounds__(256)
void postln_kernel(const float* __restrict__ Ob, const float* __restrict__ pnw,
                   const float* __restrict__ pnb, float* __restrict__ XN)
{
    const int m = blockIdx.x;
    const int b = m >> 11, l = m & 2047;
    const int t = threadIdx.x;
    float v[8];
    float s1 = 0.0f, s2 = 0.0f;
    const float* bas = Ob + (size_t)b * NHEADS * L_SEQ * HDIM + (size_t)l * HDIM;
#pragma unroll
    for (int j = 0; j < 8; j++) {
        const int c = t + j * 256;
        const int hh = c >> 6, d = c & 63;
        const float x = bas[(size_t)hh * (L_SEQ * HDIM) + d];
        v[j] = x; s1 += x; s2 += x * x;
    }
#pragma unroll
    for (int o = 1; o < 64; o <<= 1) { s1 += __shfl_xor(s1, o); s2 += __shfl_xor(s2, o); }
    __shared__ float r1[4], r2[4];
    const int w = t >> 6;
    if ((t & 63) == 0) { r1[w] = s1; r2[w] = s2; }
    __syncthreads();
    s1 = r1[0] + r1[1] + r1[2] + r1[3];
    s2 = r2[0] + r2[1] + r2[2] + r2[3];
    const float mu = s1 * (1.0f / 2048.0f);
    const float var = s2 * (1.0f / 2048.0f) - mu * mu;
    const float rstd = rsqrtf(var + EPS_);
    float* o = XN + (size_t)m * C_DIM;
#pragma unroll
    for (int j = 0; j < 8; j++) {
        const int c = t + j * 256;
        o[c] = (v[j] - mu) * rstd * pnw[c] + pnb[c];
    }
}

// ======================================================================
extern "C" void kernel_launch(void* const* d_in, const int* in_sizes, int n_in,
                              void* d_out, int out_size, void* d_ws, size_t ws_size,
                              hipStream_t stream)
{
    (void)in_sizes; (void)n_in; (void)out_size; (void)ws_size;
    const float* hidden  = (const float*)d_in[0];
    const float* Wq      = (const float*)d_in[2];
    const float* Wk      = (const float*)d_in[3];
    const float* Wv      = (const float*)d_in[4];
    const float* Wo      = (const float*)d_in[5];
    const float* W1      = (const float*)d_in[6];
    const float* b1      = (const float*)d_in[7];
    const float* wlr     = (const float*)d_in[8];
    const float* lr_bias = (const float*)d_in[9];
    const float* lt      = (const float*)d_in[10];
    const float* lnw     = (const float*)d_in[11];
    const float* lnb     = (const float*)d_in[12];
    const float* pnw     = (const float*)d_in[13];
    const float* pnb     = (const float*)d_in[14];

    const size_t TEN = (size_t)B_DIM * NHEADS * L_SEQ * HDIM;  // 16777216
    float* XQ  = (float*)d_ws;
    float* XK  = XQ + TEN;
    float* XVo = XK + TEN;
    float* LRS = XVo + TEN;
    const dim3 blk(256);

    _Float16* BThi = (_Float16*)d_out;
    _Float16* BTlo = BThi + (size_t)C_DIM * C_DIM;

    lr_kernel<<<dim3(B_DIM * L_SEQ), blk, 0, stream>>>(hidden, wlr, lr_bias, LRS);

    const float* Wmats[3] = {Wq, Wk, Wv};
    float* outs[3] = {XQ, XK, XVo};
    for (int p = 0; p < 3; p++) {
        wtrans_kernel<<<dim3(64, 64), blk, 0, stream>>>(Wmats[p], BThi, BTlo, C_DIM);
        gemm_af32<<<dim3(16, 64), blk, 0, stream>>>(hidden, BThi, BTlo,
                                                    outs[p], 0, (p < 2) ? 1 : 0);
    }
    scan_1wave<<<dim3(B_DIM * NHEADS), dim3(64), 0, stream>>>(XQ, XK, XVo, LRS,
                                                              W1, b1, lt, lnw, lnb);
    float* XN = XQ;
    _Float16* WThi = (_Float16*)XK;
    _Float16* WTlo = WThi + (size_t)OUT_DIM * C_DIM;
    postln_kernel<<<dim3(B_DIM * L_SEQ), blk, 0, stream>>>(XVo, pnw, pnb, XN);
    wtrans_kernel<<<dim3(24, 64), blk, 0, stream>>>(Wo, WThi, WTlo, OUT_DIM);
    gemm_af32<<<dim3(6, 64), blk, 0, stream>>>(XN, WThi, WTlo,
                                               (float*)d_out, 1, 0);
}

// Round 6
// 1610.686 us; speedup vs baseline: 1.1459x; 1.1459x over previous
//
#include <hip/hip_runtime.h>
#include <cstddef>
#include <cstdint>

// Problem constants
#define B_DIM   4
#define L_SEQ   2048
#define C_DIM   2048
#define OUT_DIM 768
#define NHEADS  32
#define HDIM    64
#define MBS_    16
#define NMINI   128
#define EPS_    1e-6f

typedef _Float16 half8 __attribute__((ext_vector_type(8)));
typedef float floatx4 __attribute__((ext_vector_type(4)));

__device__ __forceinline__ void glds16(const void* g, void* l) {
    __builtin_amdgcn_global_load_lds(
        (const __attribute__((address_space(1))) uint32_t*)g,
        (__attribute__((address_space(3))) uint32_t*)l, 16, 0, 0);
}

__device__ __forceinline__ void split8(const float4 a, const float4 b,
                                       half8& hi, half8& lo) {
    const float x[8] = {a.x, a.y, a.z, a.w, b.x, b.y, b.z, b.w};
#pragma unroll
    for (int e = 0; e < 8; e++) {
        const _Float16 h = (_Float16)x[e];
        hi[e] = h;
        lo[e] = (_Float16)(x[e] - (float)h);
    }
}

#define MFMA3(ACC, AH, AL, BH, BL)                                             \
    ACC = __builtin_amdgcn_mfma_f32_16x16x32_f16((AH), (BH), ACC, 0, 0, 0);    \
    ACC = __builtin_amdgcn_mfma_f32_16x16x32_f16((AH), (BL), ACC, 0, 0, 0);    \
    ACC = __builtin_amdgcn_mfma_f32_16x16x32_f16((AL), (BH), ACC, 0, 0, 0);

// Raw barrier: LDS-drain only; vmcnt (prefetch/stores) stays in flight.
#define BARRIER_LGKM() __asm volatile("s_waitcnt lgkmcnt(0)\n\ts_barrier" ::: "memory")
#define WAIT_VM0()     __asm volatile("s_waitcnt vmcnt(0)" ::: "memory")

// ======================================================================
// MFMA GEMM, A = fp32 [M][2048] split on the fly; B = fp16 hi/lo [N][K].
// (unchanged — proven R3/R4/R5)
// ======================================================================
__global__ __launch_bounds__(256)
void gemm_af32(const float* __restrict__ A,
               const _Float16* __restrict__ Bhi, const _Float16* __restrict__ Blo,
               float* __restrict__ Cout, int mode, int doRope)
{
    __shared__ __align__(16) float    sA[4096];
    __shared__ __align__(16) _Float16 sBhi[4096];
    __shared__ __align__(16) _Float16 sBlo[4096];
    const int tid = threadIdx.x;
    const int m0 = blockIdx.y * 128, n0 = blockIdx.x * 128;
    const int K = 2048;

    size_t gA[4]; float* lA[4];
#pragma unroll
    for (int I = 0; I < 4; I++) {
        const int c = I * 256 + tid;
        const int row = c >> 3, seg = (c & 7) ^ (row & 7);
        gA[I] = (size_t)(m0 + row) * K + seg * 4;
        lA[I] = &sA[c * 4];
    }
    size_t gB[2]; _Float16 *lBh[2], *lBl[2];
#pragma unroll
    for (int I = 0; I < 2; I++) {
        const int c = I * 256 + tid;
        const int row = c >> 2, seg = (c & 3) ^ ((row >> 1) & 3);
        gB[I] = (size_t)(n0 + row) * K + seg * 8;
        lBh[I] = &sBhi[c * 8];
        lBl[I] = &sBlo[c * 8];
    }

    const int lane = tid & 63, quad = lane >> 4, lc = lane & 15;
    const int wv = tid >> 6, wm = wv & 1, wn = wv >> 1;
    int offA0[4], offA1[4], offB[4];
#pragma unroll
    for (int i = 0; i < 4; i++) {
        const int rA = wm * 64 + i * 16 + lc;
        offA0[i] = (rA * 8 + ((2 * quad)     ^ (rA & 7))) * 4;
        offA1[i] = (rA * 8 + ((2 * quad + 1) ^ (rA & 7))) * 4;
    }
#pragma unroll
    for (int j = 0; j < 4; j++) {
        const int rB = wn * 64 + j * 16 + lc;
        offB[j] = (rB * 4 + (quad ^ ((rB >> 1) & 3))) * 8;
    }

    floatx4 acc[4][4];
#pragma unroll
    for (int i = 0; i < 4; i++)
#pragma unroll
        for (int j = 0; j < 4; j++) acc[i][j] = (floatx4)0.0f;

    for (int k0 = 0; k0 < K; k0 += 32) {
        __syncthreads();
#pragma unroll
        for (int I = 0; I < 4; I++) glds16(A + gA[I] + k0, lA[I]);
#pragma unroll
        for (int I = 0; I < 2; I++) {
            glds16(Bhi + gB[I] + k0, lBh[I]);
            glds16(Blo + gB[I] + k0, lBl[I]);
        }
        __syncthreads();

        half8 ah[4], al[4], bh[4], bl[4];
#pragma unroll
        for (int i = 0; i < 4; i++) {
            const float4 va = *(const float4*)&sA[offA0[i]];
            const float4 vb = *(const float4*)&sA[offA1[i]];
            split8(va, vb, ah[i], al[i]);
        }
#pragma unroll
        for (int j = 0; j < 4; j++) {
            bh[j] = *(const half8*)&sBhi[offB[j]];
            bl[j] = *(const half8*)&sBlo[offB[j]];
        }
#pragma unroll
        for (int i = 0; i < 4; i++)
#pragma unroll
            for (int j = 0; j < 4; j++) {
                MFMA3(acc[i][j], ah[i], al[i], bh[j], bl[j]);
            }
    }

    float cs[4][4], sn[4][4];
    if (doRope) {
#pragma unroll
        for (int j = 0; j < 4; j++) {
            const int ii = ((j * 16 + lc) & 63) >> 1;
            const float invf = expf(-(float)ii * 0.28782313662425574f);
#pragma unroll
            for (int r = 0; r < 4; r++) {
                const float ang = (float)(quad * 4 + r) * invf;
                sincosf(ang, &sn[j][r], &cs[j][r]);
            }
        }
    }
    const int oddcol = lc & 1;
#pragma unroll
    for (int i = 0; i < 4; i++) {
#pragma unroll
        for (int j = 0; j < 4; j++) {
            floatx4 v = acc[i][j];
            if (doRope) {
#pragma unroll
                for (int r = 0; r < 4; r++) {
                    const float partner = __shfl_xor(v[r], 1);
                    v[r] = v[r] * cs[j][r] + partner * (oddcol ? sn[j][r] : -sn[j][r]);
                }
            }
            const int n = n0 + wn * 64 + j * 16 + lc;
            if (mode == 0) {
                const int h = (n >> 6) & 31, d = n & 63;
#pragma unroll
                for (int r = 0; r < 4; r++) {
                    const int m = m0 + wm * 64 + i * 16 + quad * 4 + r;
                    const int b = m >> 11, li = m & 2047;
                    Cout[((size_t)(b * 32 + h) * 2048 + li) * 64 + d] = v[r];
                }
            } else {
#pragma unroll
                for (int r = 0; r < 4; r++) {
                    const int m = m0 + wm * 64 + i * 16 + quad * 4 + r;
                    Cout[(size_t)m * OUT_DIM + n] = v[r];
                }
            }
        }
    }
}

// ======================================================================
// Weight transpose + split
// ======================================================================
__global__ __launch_bounds__(256)
void wtrans_kernel(const float* __restrict__ W, _Float16* __restrict__ BThi,
                   _Float16* __restrict__ BTlo, int Nw)
{
    __shared__ float tile[32][33];
    const int t = threadIdx.x, tx = t & 31, ty = t >> 5;
    const int n0 = blockIdx.x * 32, k0 = blockIdx.y * 32;
    const int K = 2048;
#pragma unroll
    for (int r = 0; r < 4; r++)
        tile[ty + r * 8][tx] = W[(size_t)(k0 + ty + r * 8) * Nw + n0 + tx];
    __syncthreads();
#pragma unroll
    for (int r = 0; r < 4; r++) {
        const float val = tile[tx][ty + r * 8];
        const _Float16 hh = (_Float16)val;
        const size_t o = (size_t)(n0 + ty + r * 8) * K + k0 + tx;
        BThi[o] = hh;
        BTlo[o] = (_Float16)(val - (float)hh);
    }
}

// ======================================================================
// ttt_lr sigmoid
// ======================================================================
__global__ __launch_bounds__(256)
void lr_kernel(const float* __restrict__ hidden, const float* __restrict__ wlr,
               const float* __restrict__ lr_bias, float* __restrict__ lrs)
{
    __shared__ float sRow[2048];
    __shared__ float sPart[32][9];
    const int m = blockIdx.x;
    const int t = threadIdx.x;
    const float* row = hidden + (size_t)m * C_DIM;
#pragma unroll
    for (int j = 0; j < 8; j++) sRow[t + j * 256] = row[t + j * 256];
    __syncthreads();
    const int h = t >> 3, p = t & 7;
    const float* w = wlr + (size_t)h * C_DIM;
    float s = 0.0f;
#pragma unroll 8
    for (int k = 0; k < 64; k++) {
        const int c = k * 32 + p * 4;
        const float4 a = *(const float4*)(sRow + c);
        const float4 b = *(const float4*)(w + c);
        s += a.x * b.x + a.y * b.y + a.z * b.z + a.w * b.w;
    }
    sPart[h][p] = s;
    __syncthreads();
    if (t < 32) {
        float v = 0.0f;
#pragma unroll
        for (int p2 = 0; p2 < 8; p2++) v += sPart[t][p2];
        v += lr_bias[t];
        const float sig = 1.0f / (1.0f + expf(-v));
        lrs[((size_t)(m >> 11) * NHEADS + t) * L_SEQ + (m & 2047)] = sig;
    }
}

// ======================================================================
// MFMA TTT scan v6: 4 waves per (b,h); R4's wave-partitioned algebra,
// but (1) RAW barriers (lgkmcnt-only drain — prefetch vmcnt stays in
// flight across barriers, drained once/step at the top), (2) 5 barriers
// instead of 9 (glds-staged minibatches kill phase-1; all-wave redundant
// stat reduction kills the t<16 second-barrier pattern).
// ======================================================================
__global__ __launch_bounds__(256, 1)
void scan_v6(const float* __restrict__ XQ, const float* __restrict__ XK,
             float* __restrict__ XVo, const float* __restrict__ LRS,
             const float* __restrict__ W1i, const float* __restrict__ b1i,
             const float* __restrict__ lt, const float* __restrict__ lnw,
             const float* __restrict__ lnb)
{
    __shared__ __align__(16) float sXq[2][1024];   // [16][64] XOR-cell, dbuf
    __shared__ __align__(16) float sXk[2][1024];
    __shared__ __align__(16) float sXv[2][1024];
    __shared__ __align__(16) float sW1T[4096];     // [n][k] cell-XOR
    __shared__ __align__(16) float sGt[64 * 36];   // gradT[n][j], j 16..31 = 0
    __shared__ __align__(16) float sKt[64 * 36];   // Kt[d][j] = le[j]*Xk[j][d]
    __shared__ __align__(16) float sCf[16 * 36];   // -coeff[i][j], j 16..31 = 0
    __shared__ __align__(16) float sRedA[16 * 8];  // Z1 stats partials
    __shared__ __align__(16) float sRedB[16 * 8];  // grad partials
    __shared__ __align__(16) float sRedC[16 * 8];  // Zbar partials
    __shared__ __align__(16) float sB1[64];
    __shared__ __align__(16) float sEta[32];       // [16..31] stay zero

    const int t = threadIdx.x;
    const int lane = t & 63, q = lane >> 4, lc = lane & 15;
    const int w = t >> 6;
    const int col = 16 * w + lc;
    const int bh = blockIdx.x, h = bh & 31;

    // glds staging: wave w covers cells [w*64, w*64+64) (rows 4w..4w+3)
    int srcOffW;
    {
        const int c = w * 64 + lane;
        const int row = c >> 4, seg = (c & 15) ^ (row & 15);
        srcOffW = row * 64 + seg * 4;
    }

    // constants
    float tokR[4];
#pragma unroll
    for (int r = 0; r < 4; r++)
        tokR[r] = fmaxf(1.0f / (float)(4 * q + r + 1) + lt[4 * q + r], 0.0f);
    const float tok15 = fmaxf(1.0f / 16.0f + lt[15], 0.0f);
    const float gamC = lnw[h * 64 + col], betC = lnb[h * 64 + col];

    if (t < 64) sB1[t] = b1i[h * 64 + t];
    if (t < 32) sEta[t] = 0.0f;
    for (int z = t; z < 1024; z += 256) {          // zero pads j=16..31
        const int r = z >> 4, c = 16 + (z & 15);
        sGt[r * 36 + c] = 0.0f;
        sKt[r * 36 + c] = 0.0f;
    }
    { const int r = t >> 4, c = 16 + (t & 15); sCf[r * 36 + c] = 0.0f; }

    // W1 state (wave w owns n in [16w,16w+16)): w1s[t4][r] = W1[k=16t4+lc][n=16w+4q+r]
    float w1s[4][4];
#pragma unroll
    for (int t4 = 0; t4 < 4; t4++)
#pragma unroll
        for (int r = 0; r < 4; r++)
            w1s[t4][r] = W1i[h * 4096 + (16 * t4 + lc) * 64 + (16 * w + 4 * q + r)];
#pragma unroll
    for (int t4 = 0; t4 < 4; t4++)
#pragma unroll
        for (int r = 0; r < 4; r++) {
            const int nn = 16 * w + 4 * q + r, k = 16 * t4 + lc;
            sW1T[nn * 64 + ((((k >> 2) ^ (nn & 15)) << 2) | (k & 3))] = w1s[t4][r];
        }

    const size_t base = (size_t)bh * L_SEQ * HDIM;
    const float* xq_g = XQ + base;
    const float* xk_g = XK + base;
    float* xv_g = XVo + base;
    const float* lr_g = LRS + (size_t)bh * L_SEQ;

    // prefetch minibatch 0 into buf 0 (1 glds per tensor per wave)
    glds16(xq_g + srcOffW, &sXq[0][w * 256]);
    glds16(xk_g + srcOffW, &sXk[0][w * 256]);
    glds16(xv_g + srcOffW, &sXv[0][w * 256]);
    float clr = lr_g[lc];

    for (int n = 0; n < NMINI; n++) {
        const int buf = n & 1, nb = buf ^ 1;
        WAIT_VM0();        // own prefetch (+ old stores) drained; full step of slack
        BARRIER_LGKM();    // A: buffers complete, W1T/B1 writebacks visible

        const float etaC = clr * (1.0f / 64.0f);   // eta[lc] this step
        if (w == 0 && t < 16) sEta[t] = etaC;
        // issue next prefetch (stays in flight across ALL barriers this step)
        const int np = (n + 1) & (NMINI - 1);
        const size_t go = (size_t)np * 1024;
        glds16(xq_g + go + srcOffW, &sXq[nb][w * 256]);
        glds16(xk_g + go + srcOffW, &sXk[nb][w * 256]);
        glds16(xv_g + go + srcOffW, &sXv[nb][w * 256]);
        const float nlr = lr_g[np * 16 + lc];

        const float b1c = sB1[col];

        // Kt build: wave w handles phys cells q+4w of each row lc
        {
            const int phys = q + 4 * w;
            const float4 v = *(const float4*)&sXk[buf][lc * 64 + phys * 4];
            const int cb = 4 * (phys ^ lc);
            const float leC = tok15 * etaC;
            sKt[(cb + 0) * 36 + lc] = v.x * leC;
            sKt[(cb + 1) * 36 + lc] = v.y * leC;
            sKt[(cb + 2) * 36 + lc] = v.z * leC;
            sKt[(cb + 3) * 36 + lc] = v.w * leC;
        }

        // A-fragments Xq/Xk (rows = lc, K = 64 over 2 frags)
        half8 qh[2], ql[2], kh[2], kl[2], wh[2], wl[2];
#pragma unroll
        for (int f = 0; f < 2; f++) {
            const int ca = (8 * f + 2 * q) ^ lc, cb2 = (8 * f + 2 * q + 1) ^ lc;
            {
                const float4 u0 = *(const float4*)&sXq[buf][lc * 64 + ca * 4];
                const float4 u1 = *(const float4*)&sXq[buf][lc * 64 + cb2 * 4];
                split8(u0, u1, qh[f], ql[f]);
            }
            {
                const float4 u0 = *(const float4*)&sXk[buf][lc * 64 + ca * 4];
                const float4 u1 = *(const float4*)&sXk[buf][lc * 64 + cb2 * 4];
                split8(u0, u1, kh[f], kl[f]);
            }
            {
                const int rw = 16 * w + lc;
                const float4 u0 = *(const float4*)&sW1T[rw * 64 + ca * 4];
                const float4 u1 = *(const float4*)&sW1T[rw * 64 + cb2 * 4];
                split8(u0, u1, wh[f], wl[f]);
            }
        }

        // forward MFMAs (wave's 16-col tile)
        floatx4 at = (floatx4)0.0f, z1a = (floatx4)0.0f, zba = (floatx4)0.0f;
        if (w == 0) {
#pragma unroll
            for (int f = 0; f < 2; f++) { MFMA3(at, qh[f], ql[f], kh[f], kl[f]); }
        }
#pragma unroll
        for (int f = 0; f < 2; f++) {
            MFMA3(z1a, kh[f], kl[f], wh[f], wl[f]);
            MFMA3(zba, qh[f], ql[f], wh[f], wl[f]);
        }

        // ---- Z1 stats: quad-shfl partials -> sRedA -> barrier -> all-reduce
        float z[4], s1[4], s2[4];
#pragma unroll
        for (int r = 0; r < 4; r++) { z[r] = z1a[r] + b1c; s1[r] = z[r]; s2[r] = z[r] * z[r]; }
#pragma unroll
        for (int o = 1; o < 16; o <<= 1)
#pragma unroll
            for (int r = 0; r < 4; r++) { s1[r] += __shfl_xor(s1[r], o); s2[r] += __shfl_xor(s2[r], o); }
        if (lc == 0)
#pragma unroll
            for (int r = 0; r < 4; r++) {
                sRedA[(4 * q + r) * 8 + w] = s1[r];
                sRedA[(4 * q + r) * 8 + 4 + w] = s2[r];
            }
        BARRIER_LGKM();    // B
        float mu[4], rs[4];
#pragma unroll
        for (int r = 0; r < 4; r++) {
            const float4 a = *(const float4*)&sRedA[(4 * q + r) * 8];
            const float4 b = *(const float4*)&sRedA[(4 * q + r) * 8 + 4];
            const float m1 = (a.x + a.y + a.z + a.w) * (1.0f / 64.0f);
            mu[r] = m1;
            rs[r] = rsqrtf((b.x + b.y + b.z + b.w) * (1.0f / 64.0f) - m1 * m1 + EPS_);
        }

        // ---- LN-L2 grad
        float gg[4], xh[4], g1[4], g2[4];
#pragma unroll
        for (int r = 0; r < 4; r++) {
            const int row = 4 * q + r;
            const int ad = row * 64 + (((((col >> 2) ^ row) & 15) << 2) | (col & 3));
            xh[r] = (z[r] - mu[r]) * rs[r];
            const float tgt = sXv[buf][ad] - sXk[buf][ad];
            gg[r] = (gamC * xh[r] + betC - tgt) * gamC;
            g1[r] = gg[r];
            g2[r] = gg[r] * xh[r];
        }
#pragma unroll
        for (int o = 1; o < 16; o <<= 1)
#pragma unroll
            for (int r = 0; r < 4; r++) { g1[r] += __shfl_xor(g1[r], o); g2[r] += __shfl_xor(g2[r], o); }
        if (lc == 0)
#pragma unroll
            for (int r = 0; r < 4; r++) {
                sRedB[(4 * q + r) * 8 + w] = g1[r];
                sRedB[(4 * q + r) * 8 + 4 + w] = g2[r];
            }
        BARRIER_LGKM();    // D
        {
            float4 g4;
#pragma unroll
            for (int r = 0; r < 4; r++) {
                const float4 a = *(const float4*)&sRedB[(4 * q + r) * 8];
                const float4 b = *(const float4*)&sRedB[(4 * q + r) * 8 + 4];
                const float G1 = a.x + a.y + a.z + a.w;
                const float G2 = b.x + b.y + b.z + b.w;
                ((float*)&g4)[r] = (64.0f * gg[r] - G1 - xh[r] * G2) * rs[r] * (1.0f / 64.0f);
            }
            *(float4*)&sGt[col * 36 + 4 * q] = g4;   // gradT[n=col][j=4q+r]
        }
        if (w == 0) {
#pragma unroll
            for (int r = 0; r < 4; r++) {
                const int i = 4 * q + r;
                sCf[i * 36 + lc] = (lc <= i) ? -tokR[r] * etaC * (at[r] + 1.0f) : 0.0f;
            }
        }
        BARRIER_LGKM();    // E

        // ---- Zbar correction + W1 update
        half8 cfh, cfl, gth, gtl;
        {
            const float4 u0 = *(const float4*)&sCf[lc * 36 + 8 * q];
            const float4 u1 = *(const float4*)&sCf[lc * 36 + 8 * q + 4];
            split8(u0, u1, cfh, cfl);
        }
        {
            const int rw = 16 * w + lc;
            const float4 u0 = *(const float4*)&sGt[rw * 36 + 8 * q];
            const float4 u1 = *(const float4*)&sGt[rw * 36 + 8 * q + 4];
            split8(u0, u1, gth, gtl);
        }
        MFMA3(zba, cfh, cfl, gth, gtl);
#pragma unroll
        for (int t4 = 0; t4 < 4; t4++) {
            half8 kth, ktl;
            const float4 u0 = *(const float4*)&sKt[(16 * t4 + lc) * 36 + 8 * q];
            const float4 u1 = *(const float4*)&sKt[(16 * t4 + lc) * 36 + 8 * q + 4];
            split8(u0, u1, kth, ktl);
            floatx4 up = (floatx4)0.0f;
            MFMA3(up, gth, gtl, kth, ktl);
#pragma unroll
            for (int r = 0; r < 4; r++) w1s[t4][r] -= up[r];
        }

        // ---- Zbar stats
        float z2[4];
#pragma unroll
        for (int r = 0; r < 4; r++) { z2[r] = zba[r] + b1c; s1[r] = z2[r]; s2[r] = z2[r] * z2[r]; }
#pragma unroll
        for (int o = 1; o < 16; o <<= 1)
#pragma unroll
            for (int r = 0; r < 4; r++) { s1[r] += __shfl_xor(s1[r], o); s2[r] += __shfl_xor(s2[r], o); }
        if (lc == 0)
#pragma unroll
            for (int r = 0; r < 4; r++) {
                sRedC[(4 * q + r) * 8 + w] = s1[r];
                sRedC[(4 * q + r) * 8 + 4 + w] = s2[r];
            }
        BARRIER_LGKM();    // F
#pragma unroll
        for (int r = 0; r < 4; r++) {
            const float4 a = *(const float4*)&sRedC[(4 * q + r) * 8];
            const float4 b = *(const float4*)&sRedC[(4 * q + r) * 8 + 4];
            const float m1 = (a.x + a.y + a.z + a.w) * (1.0f / 64.0f);
            mu[r] = m1;
            rs[r] = rsqrtf((b.x + b.y + b.z + b.w) * (1.0f / 64.0f) - m1 * m1 + EPS_);
        }
        // out = xq + LN(Zbar)  (global stores stay in flight past barriers)
#pragma unroll
        for (int r = 0; r < 4; r++) {
            const int row = 4 * q + r;
            const int ad = row * 64 + (((((col >> 2) ^ row) & 15) << 2) | (col & 3));
            xv_g[n * 1024 + row * 64 + col] =
                sXq[buf][ad] + gamC * ((z2[r] - mu[r]) * rs[r]) + betC;
        }

        // b1 update (q2/q3 see zero-padded eta)
        {
            const float4 e0 = *(const float4*)&sEta[8 * q];
            const float4 e1 = *(const float4*)&sEta[8 * q + 4];
            const float ev[8] = {e0.x, e0.y, e0.z, e0.w, e1.x, e1.y, e1.z, e1.w};
            float p = 0.0f;
#pragma unroll
            for (int jj = 0; jj < 8; jj++)
                p += ((float)gth[jj] + (float)gtl[jj]) * ev[jj];
            p += __shfl_xor(p, 16);
            if (q == 0) sB1[col] -= tok15 * p;
        }

        // W1T writeback (visible after next step's barrier A)
#pragma unroll
        for (int t4 = 0; t4 < 4; t4++)
#pragma unroll
            for (int r = 0; r < 4; r++) {
                const int nn = 16 * w + 4 * q + r, k = 16 * t4 + lc;
                sW1T[nn * 64 + ((((k >> 2) ^ (nn & 15)) << 2) | (k & 3))] = w1s[t4][r];
            }
        clr = nlr;
    }
}

// ======================================================================
// post-norm: gather (B,NH,L,HD) -> LN over C=2048 -> fp32 (B,L,C)
// ======================================================================
__global__ __launch_bounds__(256)
void postln_kernel(const float* __restrict__ Ob, const float* __restrict__ pnw,
                   const float* __restrict__ pnb, float* __restrict__ XN)
{
    const int m = blockIdx.x;
    const int b = m >> 11, l = m & 2047;
    const int t = threadIdx.x;
    float v[8];
    float s1 = 0.0f, s2 = 0.0f;
    const float* bas = Ob + (size_t)b * NHEADS * L_SEQ * HDIM + (size_t)l * HDIM;
#pragma unroll
    for (int j = 0; j < 8; j++) {
        const int c = t + j * 256;
        const int hh = c >> 6, d = c & 63;
        const float x = bas[(size_t)hh * (L_SEQ * HDIM) + d];
        v[j] = x; s1 += x; s2 += x * x;
    }
#pragma unroll
    for (int o = 1; o < 64; o <<= 1) { s1 += __shfl_xor(s1, o); s2 += __shfl_xor(s2, o); }
    __shared__ float r1[4], r2[4];
    const int w = t >> 6;
    if ((t & 63) == 0) { r1[w] = s1; r2[w] = s2; }
    __syncthreads();
    s1 = r1[0] + r1[1] + r1[2] + r1[3];
    s2 = r2[0] + r2[1] + r2[2] + r2[3];
    const float mu = s1 * (1.0f / 2048.0f);
    const float var = s2 * (1.0f / 2048.0f) - mu * mu;
    const float rstd = rsqrtf(var + EPS_);
    float* o = XN + (size_t)m * C_DIM;
#pragma unroll
    for (int j = 0; j < 8; j++) {
        const int c = t + j * 256;
        o[c] = (v[j] - mu) * rstd * pnw[c] + pnb[c];
    }
}

// ======================================================================
extern "C" void kernel_launch(void* const* d_in, const int* in_sizes, int n_in,
                              void* d_out, int out_size, void* d_ws, size_t ws_size,
                              hipStream_t stream)
{
    (void)in_sizes; (void)n_in; (void)out_size; (void)ws_size;
    const float* hidden  = (const float*)d_in[0];
    const float* Wq      = (const float*)d_in[2];
    const float* Wk      = (const float*)d_in[3];
    const float* Wv      = (const float*)d_in[4];
    const float* Wo      = (const float*)d_in[5];
    const float* W1      = (const float*)d_in[6];
    const float* b1      = (const float*)d_in[7];
    const float* wlr     = (const float*)d_in[8];
    const float* lr_bias = (const float*)d_in[9];
    const float* lt      = (const float*)d_in[10];
    const float* lnw     = (const float*)d_in[11];
    const float* lnb     = (const float*)d_in[12];
    const float* pnw     = (const float*)d_in[13];
    const float* pnb     = (const float*)d_in[14];

    const size_t TEN = (size_t)B_DIM * NHEADS * L_SEQ * HDIM;  // 16777216
    float* XQ  = (float*)d_ws;
    float* XK  = XQ + TEN;
    float* XVo = XK + TEN;
    float* LRS = XVo + TEN;
    const dim3 blk(256);

    _Float16* BThi = (_Float16*)d_out;
    _Float16* BTlo = BThi + (size_t)C_DIM * C_DIM;

    lr_kernel<<<dim3(B_DIM * L_SEQ), blk, 0, stream>>>(hidden, wlr, lr_bias, LRS);

    const float* Wmats[3] = {Wq, Wk, Wv};
    float* outs[3] = {XQ, XK, XVo};
    for (int p = 0; p < 3; p++) {
        wtrans_kernel<<<dim3(64, 64), blk, 0, stream>>>(Wmats[p], BThi, BTlo, C_DIM);
        gemm_af32<<<dim3(16, 64), blk, 0, stream>>>(hidden, BThi, BTlo,
                                                    outs[p], 0, (p < 2) ? 1 : 0);
    }
    scan_v6<<<dim3(B_DIM * NHEADS), blk, 0, stream>>>(XQ, XK, XVo, LRS,
                                                      W1, b1, lt, lnw, lnb);
    float* XN = XQ;
    _Float16* WThi = (_Float16*)XK;
    _Float16* WTlo = WThi + (size_t)OUT_DIM * C_DIM;
    postln_kernel<<<dim3(B_DIM * L_SEQ), blk, 0, stream>>>(XVo, pnw, pnb, XN);
    wtrans_kernel<<<dim3(24, 64), blk, 0, stream>>>(Wo, WThi, WTlo, OUT_DIM);
    gemm_af32<<<dim3(6, 64), blk, 0, stream>>>(XN, WThi, WTlo,
                                               (float*)d_out, 1, 0);
}

// Round 8
// 1511.694 us; speedup vs baseline: 1.2210x; 1.0655x over previous
//
#include <hip/hip_runtime.h>
#include <cstddef>
#include <cstdint>

// Problem constants
#define B_DIM   4
#define L_SEQ   2048
#define C_DIM   2048
#define OUT_DIM 768
#define NHEADS  32
#define HDIM    64
#define MBS_    16
#define NMINI   128
#define EPS_    1e-6f

typedef _Float16 half8 __attribute__((ext_vector_type(8)));
typedef float floatx4 __attribute__((ext_vector_type(4)));

__device__ __forceinline__ void glds16(const void* g, void* l) {
    __builtin_amdgcn_global_load_lds(
        (const __attribute__((address_space(1))) uint32_t*)g,
        (__attribute__((address_space(3))) uint32_t*)l, 16, 0, 0);
}

__device__ __forceinline__ void split8(const float4 a, const float4 b,
                                       half8& hi, half8& lo) {
    const float x[8] = {a.x, a.y, a.z, a.w, b.x, b.y, b.z, b.w};
#pragma unroll
    for (int e = 0; e < 8; e++) {
        const _Float16 h = (_Float16)x[e];
        hi[e] = h;
        lo[e] = (_Float16)(x[e] - (float)h);
    }
}

__device__ __forceinline__ void split8f(const float x[8], half8& hi, half8& lo) {
#pragma unroll
    for (int e = 0; e < 8; e++) {
        const _Float16 h = (_Float16)x[e];
        hi[e] = h;
        lo[e] = (_Float16)(x[e] - (float)h);
    }
}

#define MFMA3(ACC, AH, AL, BH, BL)                                             \
    ACC = __builtin_amdgcn_mfma_f32_16x16x32_f16((AH), (BH), ACC, 0, 0, 0);    \
    ACC = __builtin_amdgcn_mfma_f32_16x16x32_f16((AH), (BL), ACC, 0, 0, 0);    \
    ACC = __builtin_amdgcn_mfma_f32_16x16x32_f16((AL), (BH), ACC, 0, 0, 0);

// ======================================================================
// MFMA GEMM, A = fp32 [M][2048] split on the fly; B = fp16 hi/lo [N][K].
// (unchanged — proven R3..R6)
// ======================================================================
__global__ __launch_bounds__(256)
void gemm_af32(const float* __restrict__ A,
               const _Float16* __restrict__ Bhi, const _Float16* __restrict__ Blo,
               float* __restrict__ Cout, int mode, int doRope)
{
    __shared__ __align__(16) float    sA[4096];
    __shared__ __align__(16) _Float16 sBhi[4096];
    __shared__ __align__(16) _Float16 sBlo[4096];
    const int tid = threadIdx.x;
    const int m0 = blockIdx.y * 128, n0 = blockIdx.x * 128;
    const int K = 2048;

    size_t gA[4]; float* lA[4];
#pragma unroll
    for (int I = 0; I < 4; I++) {
        const int c = I * 256 + tid;
        const int row = c >> 3, seg = (c & 7) ^ (row & 7);
        gA[I] = (size_t)(m0 + row) * K + seg * 4;
        lA[I] = &sA[c * 4];
    }
    size_t gB[2]; _Float16 *lBh[2], *lBl[2];
#pragma unroll
    for (int I = 0; I < 2; I++) {
        const int c = I * 256 + tid;
        const int row = c >> 2, seg = (c & 3) ^ ((row >> 1) & 3);
        gB[I] = (size_t)(n0 + row) * K + seg * 8;
        lBh[I] = &sBhi[c * 8];
        lBl[I] = &sBlo[c * 8];
    }

    const int lane = tid & 63, quad = lane >> 4, lc = lane & 15;
    const int wv = tid >> 6, wm = wv & 1, wn = wv >> 1;
    int offA0[4], offA1[4], offB[4];
#pragma unroll
    for (int i = 0; i < 4; i++) {
        const int rA = wm * 64 + i * 16 + lc;
        offA0[i] = (rA * 8 + ((2 * quad)     ^ (rA & 7))) * 4;
        offA1[i] = (rA * 8 + ((2 * quad + 1) ^ (rA & 7))) * 4;
    }
#pragma unroll
    for (int j = 0; j < 4; j++) {
        const int rB = wn * 64 + j * 16 + lc;
        offB[j] = (rB * 4 + (quad ^ ((rB >> 1) & 3))) * 8;
    }

    floatx4 acc[4][4];
#pragma unroll
    for (int i = 0; i < 4; i++)
#pragma unroll
        for (int j = 0; j < 4; j++) acc[i][j] = (floatx4)0.0f;

    for (int k0 = 0; k0 < K; k0 += 32) {
        __syncthreads();
#pragma unroll
        for (int I = 0; I < 4; I++) glds16(A + gA[I] + k0, lA[I]);
#pragma unroll
        for (int I = 0; I < 2; I++) {
            glds16(Bhi + gB[I] + k0, lBh[I]);
            glds16(Blo + gB[I] + k0, lBl[I]);
        }
        __syncthreads();

        half8 ah[4], al[4], bh[4], bl[4];
#pragma unroll
        for (int i = 0; i < 4; i++) {
            const float4 va = *(const float4*)&sA[offA0[i]];
            const float4 vb = *(const float4*)&sA[offA1[i]];
            split8(va, vb, ah[i], al[i]);
        }
#pragma unroll
        for (int j = 0; j < 4; j++) {
            bh[j] = *(const half8*)&sBhi[offB[j]];
            bl[j] = *(const half8*)&sBlo[offB[j]];
        }
#pragma unroll
        for (int i = 0; i < 4; i++)
#pragma unroll
            for (int j = 0; j < 4; j++) {
                MFMA3(acc[i][j], ah[i], al[i], bh[j], bl[j]);
            }
    }

    float cs[4][4], sn[4][4];
    if (doRope) {
#pragma unroll
        for (int j = 0; j < 4; j++) {
            const int ii = ((j * 16 + lc) & 63) >> 1;
            const float invf = expf(-(float)ii * 0.28782313662425574f);
#pragma unroll
            for (int r = 0; r < 4; r++) {
                const float ang = (float)(quad * 4 + r) * invf;
                sincosf(ang, &sn[j][r], &cs[j][r]);
            }
        }
    }
    const int oddcol = lc & 1;
#pragma unroll
    for (int i = 0; i < 4; i++) {
#pragma unroll
        for (int j = 0; j < 4; j++) {
            floatx4 v = acc[i][j];
            if (doRope) {
#pragma unroll
                for (int r = 0; r < 4; r++) {
                    const float partner = __shfl_xor(v[r], 1);
                    v[r] = v[r] * cs[j][r] + partner * (oddcol ? sn[j][r] : -sn[j][r]);
                }
            }
            const int n = n0 + wn * 64 + j * 16 + lc;
            if (mode == 0) {
                const int h = (n >> 6) & 31, d = n & 63;
#pragma unroll
                for (int r = 0; r < 4; r++) {
                    const int m = m0 + wm * 64 + i * 16 + quad * 4 + r;
                    const int b = m >> 11, li = m & 2047;
                    Cout[((size_t)(b * 32 + h) * 2048 + li) * 64 + d] = v[r];
                }
            } else {
#pragma unroll
                for (int r = 0; r < 4; r++) {
                    const int m = m0 + wm * 64 + i * 16 + quad * 4 + r;
                    Cout[(size_t)m * OUT_DIM + n] = v[r];
                }
            }
        }
    }
}

// ======================================================================
// Weight transpose + split
// ======================================================================
__global__ __launch_bounds__(256)
void wtrans_kernel(const float* __restrict__ W, _Float16* __restrict__ BThi,
                   _Float16* __restrict__ BTlo, int Nw)
{
    __shared__ float tile[32][33];
    const int t = threadIdx.x, tx = t & 31, ty = t >> 5;
    const int n0 = blockIdx.x * 32, k0 = blockIdx.y * 32;
    const int K = 2048;
#pragma unroll
    for (int r = 0; r < 4; r++)
        tile[ty + r * 8][tx] = W[(size_t)(k0 + ty + r * 8) * Nw + n0 + tx];
    __syncthreads();
#pragma unroll
    for (int r = 0; r < 4; r++) {
        const float val = tile[tx][ty + r * 8];
        const _Float16 hh = (_Float16)val;
        const size_t o = (size_t)(n0 + ty + r * 8) * K + k0 + tx;
        BThi[o] = hh;
        BTlo[o] = (_Float16)(val - (float)hh);
    }
}

// ======================================================================
// ttt_lr sigmoid
// ======================================================================
__global__ __launch_bounds__(256)
void lr_kernel(const float* __restrict__ hidden, const float* __restrict__ wlr,
               const float* __restrict__ lr_bias, float* __restrict__ lrs)
{
    __shared__ float sRow[2048];
    __shared__ float sPart[32][9];
    const int m = blockIdx.x;
    const int t = threadIdx.x;
    const float* row = hidden + (size_t)m * C_DIM;
#pragma unroll
    for (int j = 0; j < 8; j++) sRow[t + j * 256] = row[t + j * 256];
    __syncthreads();
    const int h = t >> 3, p = t & 7;
    const float* w = wlr + (size_t)h * C_DIM;
    float s = 0.0f;
#pragma unroll 8
    for (int k = 0; k < 64; k++) {
        const int c = k * 32 + p * 4;
        const float4 a = *(const float4*)(sRow + c);
        const float4 b = *(const float4*)(w + c);
        s += a.x * b.x + a.y * b.y + a.z * b.z + a.w * b.w;
    }
    sPart[h][p] = s;
    __syncthreads();
    if (t < 32) {
        float v = 0.0f;
#pragma unroll
        for (int p2 = 0; p2 < 8; p2++) v += sPart[t][p2];
        v += lr_bias[t];
        const float sig = 1.0f / (1.0f + expf(-v));
        lrs[((size_t)(m >> 11) * NHEADS + t) * L_SEQ + (m & 2047)] = sig;
    }
}

// ======================================================================
// MFMA TTT scan v8: 4 waves per (b,h), partitioned (16 cols/wave),
// __syncthreads only (3 per step). gradT + eta + b1 sums move to
// in-wave shuffles (no sGt/sEta); W1T LDS is wave-local; one barrier
// per stats reduction. Staging = register prefetch + LDS stores.
// ======================================================================
__global__ __launch_bounds__(256, 1)
void scan_v8(const float* __restrict__ XQ, const float* __restrict__ XK,
             float* __restrict__ XVo, const float* __restrict__ LRS,
             const float* __restrict__ W1i, const float* __restrict__ b1i,
             const float* __restrict__ lt, const float* __restrict__ lnw,
             const float* __restrict__ lnb)
{
    __shared__ __align__(16) float sXq[2][1024];   // [16][64] XOR-cell, dbuf
    __shared__ __align__(16) float sXk[2][1024];
    __shared__ __align__(16) float sXv[2][1024];
    __shared__ __align__(16) float sW1T[4096];     // [n][k] cell-XOR; wave-local rows
    __shared__ __align__(16) float sKt[64 * 36];   // Kt[d][j], j 16..31 = 0
    __shared__ __align__(16) float sCf[16 * 36];   // -coeff[i][j], j 16..31 = 0
    __shared__ __align__(16) float sRedA[128];     // Z1 partials [row][s1:w|s2:4+w]
    __shared__ __align__(16) float sRedB[128];     // grad partials
    __shared__ __align__(16) float sRedC[128];     // Zbar partials
    __shared__ __align__(16) float sB1[64];

    const int t = threadIdx.x;
    const int lane = t & 63, q = lane >> 4, lc = lane & 15;
    const int w = t >> 6;
    const int col = 16 * w + lc;                   // this lane's output column
    const int bh = blockIdx.x, h = bh & 31;

    // staging map: wave w covers cells [w*64, w*64+64) => rows 4w+q, XOR seg
    int srcOffW, ldsOff;
    {
        const int c = w * 64 + lane;
        const int row = c >> 4, seg = (c & 15) ^ (row & 15);
        srcOffW = row * 64 + seg * 4;
        ldsOff = c * 4;
    }

    float tokR[4];
#pragma unroll
    for (int r = 0; r < 4; r++)
        tokR[r] = fmaxf(1.0f / (float)(4 * q + r + 1) + lt[4 * q + r], 0.0f);
    const float tok15 = fmaxf(1.0f / 16.0f + lt[15], 0.0f);
    const float gamC = lnw[h * 64 + col], betC = lnb[h * 64 + col];

    if (t < 64) sB1[t] = b1i[h * 64 + t];
    for (int z = t; z < 1024; z += 256) {          // sKt pads j=16..31
        const int r = z >> 4, c = 16 + (z & 15);
        sKt[r * 36 + c] = 0.0f;
    }
    { const int r = t >> 4, c = 16 + (t & 15); sCf[r * 36 + c] = 0.0f; }

    // W1 state: w1s[t4][r] = W1T[n=16w+4q+r][k=16t4+lc] = W1[k][n]
    float w1s[4][4];
#pragma unroll
    for (int t4 = 0; t4 < 4; t4++)
#pragma unroll
        for (int r = 0; r < 4; r++)
            w1s[t4][r] = W1i[h * 4096 + (16 * t4 + lc) * 64 + (16 * w + 4 * q + r)];
#pragma unroll
    for (int t4 = 0; t4 < 4; t4++)
#pragma unroll
        for (int r = 0; r < 4; r++) {
            const int nn = 16 * w + 4 * q + r, k = 16 * t4 + lc;
            sW1T[nn * 64 + ((((k >> 2) ^ (nn & 15)) << 2) | (k & 3))] = w1s[t4][r];
        }

    const size_t base = (size_t)bh * L_SEQ * HDIM;
    const float* xq_g = XQ + base;
    const float* xk_g = XK + base;
    float* xv_g = XVo + base;
    const float* lr_g = LRS + (size_t)bh * L_SEQ;

    // stage minibatch 0 into buf 0
    {
        const float4 q0 = *(const float4*)(xq_g + srcOffW);
        const float4 k0 = *(const float4*)(xk_g + srcOffW);
        const float4 v0 = *(const float4*)(xv_g + srcOffW);
        *(float4*)&sXq[0][ldsOff] = q0;
        *(float4*)&sXk[0][ldsOff] = k0;
        *(float4*)&sXv[0][ldsOff] = v0;
    }
    float clr = lr_g[lc];
    __syncthreads();   // plays F(-1)

    // per-lane LDS addresses for own-slice scalar reads (row 4q+r, col)
    int adR[4];
#pragma unroll
    for (int r = 0; r < 4; r++) {
        const int row = 4 * q + r;
        adR[r] = row * 64 + (((((col >> 2) ^ row) & 15) << 2) | (col & 3));
    }

    for (int n = 0; n < NMINI; n++) {
        const int buf = n & 1, nb = buf ^ 1;

        // ---- step top (all data valid since last barrier) ----
        const int np = (n + 1) & (NMINI - 1);
        const size_t go = (size_t)np * 1024;
        const float4 nq = *(const float4*)(xq_g + go + srcOffW);
        const float4 nk = *(const float4*)(xk_g + go + srcOffW);
        const float4 nv = *(const float4*)(xv_g + go + srcOffW);
        const float nlr = lr_g[np * 16 + lc];

        const float etaC = clr * (1.0f / 64.0f);   // eta[lc]
        const float b1c = sB1[col];

        // own-slice scalar reads for grad targets and out residual
        float xvR[4], xkR[4], xqR[4];
#pragma unroll
        for (int r = 0; r < 4; r++) {
            xvR[r] = sXv[buf][adR[r]];
            xkR[r] = sXk[buf][adR[r]];
            xqR[r] = sXq[buf][adR[r]];
        }

        // Kt build: wave w handles phys cells q+4w of each row lc
        {
            const int phys = q + 4 * w;
            const float4 v = *(const float4*)&sXk[buf][lc * 64 + phys * 4];
            const int cb = 4 * (phys ^ lc);
            const float leC = tok15 * etaC;
            sKt[(cb + 0) * 36 + lc] = v.x * leC;
            sKt[(cb + 1) * 36 + lc] = v.y * leC;
            sKt[(cb + 2) * 36 + lc] = v.z * leC;
            sKt[(cb + 3) * 36 + lc] = v.w * leC;
        }

        // fragments (Xq/Xk rows = lc; W1T own rows 16w+lc)
        half8 qh[2], ql[2], kh[2], kl[2], wh[2], wl[2];
#pragma unroll
        for (int f = 0; f < 2; f++) {
            const int ca = (8 * f + 2 * q) ^ lc, cb2 = (8 * f + 2 * q + 1) ^ lc;
            {
                const float4 u0 = *(const float4*)&sXq[buf][lc * 64 + ca * 4];
                const float4 u1 = *(const float4*)&sXq[buf][lc * 64 + cb2 * 4];
                split8(u0, u1, qh[f], ql[f]);
            }
            {
                const float4 u0 = *(const float4*)&sXk[buf][lc * 64 + ca * 4];
                const float4 u1 = *(const float4*)&sXk[buf][lc * 64 + cb2 * 4];
                split8(u0, u1, kh[f], kl[f]);
            }
            {
                const int rw = 16 * w + lc;
                const float4 u0 = *(const float4*)&sW1T[rw * 64 + ca * 4];
                const float4 u1 = *(const float4*)&sW1T[rw * 64 + cb2 * 4];
                split8(u0, u1, wh[f], wl[f]);
            }
        }

        // forward MFMAs
        floatx4 at = (floatx4)0.0f, z1a = (floatx4)0.0f, zba = (floatx4)0.0f;
        if (w == 0) {
#pragma unroll
            for (int f = 0; f < 2; f++) { MFMA3(at, qh[f], ql[f], kh[f], kl[f]); }
        }
#pragma unroll
        for (int f = 0; f < 2; f++) {
            MFMA3(z1a, kh[f], kl[f], wh[f], wl[f]);
            MFMA3(zba, qh[f], ql[f], wh[f], wl[f]);
        }

        // cf write (wave 0, before barrier B)
        if (w == 0) {
#pragma unroll
            for (int r = 0; r < 4; r++) {
                const int i = 4 * q + r;
                sCf[i * 36 + lc] = (lc <= i) ? -tokR[r] * etaC * (at[r] + 1.0f) : 0.0f;
            }
        }

        // Z1 partials
        float z[4], s1[4], s2[4];
#pragma unroll
        for (int r = 0; r < 4; r++) { z[r] = z1a[r] + b1c; s1[r] = z[r]; s2[r] = z[r] * z[r]; }
#pragma unroll
        for (int o = 1; o < 16; o <<= 1)
#pragma unroll
            for (int r = 0; r < 4; r++) { s1[r] += __shfl_xor(s1[r], o); s2[r] += __shfl_xor(s2[r], o); }
        if (lc == 0)
#pragma unroll
            for (int r = 0; r < 4; r++) {
                sRedA[(4 * q + r) * 8 + w] = s1[r];
                sRedA[(4 * q + r) * 8 + 4 + w] = s2[r];
            }
        __syncthreads();   // B

        float mu[4], rs[4];
#pragma unroll
        for (int r = 0; r < 4; r++) {
            const float4 a = *(const float4*)&sRedA[(4 * q + r) * 8];
            const float4 b = *(const float4*)&sRedA[(4 * q + r) * 8 + 4];
            const float m1 = (a.x + a.y + a.z + a.w) * (1.0f / 64.0f);
            mu[r] = m1;
            rs[r] = rsqrtf((b.x + b.y + b.z + b.w) * (1.0f / 64.0f) - m1 * m1 + EPS_);
        }

        // grad partials
        float gg[4], xh[4], g1[4], g2[4];
#pragma unroll
        for (int r = 0; r < 4; r++) {
            xh[r] = (z[r] - mu[r]) * rs[r];
            const float tgt = xvR[r] - xkR[r];
            gg[r] = (gamC * xh[r] + betC - tgt) * gamC;
            g1[r] = gg[r];
            g2[r] = gg[r] * xh[r];
        }
#pragma unroll
        for (int o = 1; o < 16; o <<= 1)
#pragma unroll
            for (int r = 0; r < 4; r++) { g1[r] += __shfl_xor(g1[r], o); g2[r] += __shfl_xor(g2[r], o); }
        if (lc == 0)
#pragma unroll
            for (int r = 0; r < 4; r++) {
                sRedB[(4 * q + r) * 8 + w] = g1[r];
                sRedB[(4 * q + r) * 8 + 4 + w] = g2[r];
            }
        __syncthreads();   // C

        // grad finalize — registers only
        float gradReg[4];
#pragma unroll
        for (int r = 0; r < 4; r++) {
            const float4 a = *(const float4*)&sRedB[(4 * q + r) * 8];
            const float4 b = *(const float4*)&sRedB[(4 * q + r) * 8 + 4];
            const float G1 = a.x + a.y + a.z + a.w;
            const float G2 = b.x + b.y + b.z + b.w;
            gradReg[r] = (64.0f * gg[r] - G1 - xh[r] * G2) * rs[r] * (1.0f / 64.0f);
        }
        // gradT fragments via in-wave shuffles: element jj = grad[8q+jj][col]
        half8 gth, gtl;
        {
            float gv[8];
#pragma unroll
            for (int jj = 0; jj < 8; jj++) {
                const float v = __shfl(gradReg[jj & 3], ((q * 8 + jj) >> 2) * 16 + lc);
                gv[jj] = (q < 2) ? v : 0.0f;    // j' >= 16 is zero pad (K=32)
            }
            split8f(gv, gth, gtl);
        }
        // Zbar correction
        {
            half8 cfh, cfl;
            const float4 u0 = *(const float4*)&sCf[lc * 36 + 8 * q];
            const float4 u1 = *(const float4*)&sCf[lc * 36 + 8 * q + 4];
            split8(u0, u1, cfh, cfl);
            MFMA3(zba, cfh, cfl, gth, gtl);
        }
        // W1 update
#pragma unroll
        for (int t4 = 0; t4 < 4; t4++) {
            half8 kth, ktl;
            const float4 u0 = *(const float4*)&sKt[(16 * t4 + lc) * 36 + 8 * q];
            const float4 u1 = *(const float4*)&sKt[(16 * t4 + lc) * 36 + 8 * q + 4];
            split8(u0, u1, kth, ktl);
            floatx4 up = (floatx4)0.0f;
            MFMA3(up, gth, gtl, kth, ktl);
#pragma unroll
            for (int r = 0; r < 4; r++) w1s[t4][r] -= up[r];
        }
        // b1 update via shuffles (before barrier F)
        {
            float p = 0.0f;
#pragma unroll
            for (int r = 0; r < 4; r++)
                p += __shfl(etaC, 4 * q + r) * gradReg[r];
            p += __shfl_xor(p, 16);
            p += __shfl_xor(p, 32);
            if (q == 0) sB1[col] -= tok15 * p;
        }
        // staging stores for next minibatch (after C — prior readers drained)
        *(float4*)&sXq[nb][ldsOff] = nq;
        *(float4*)&sXk[nb][ldsOff] = nk;
        *(float4*)&sXv[nb][ldsOff] = nv;
        // W1T writeback (wave-local rows)
#pragma unroll
        for (int t4 = 0; t4 < 4; t4++)
#pragma unroll
            for (int r = 0; r < 4; r++) {
                const int nn = 16 * w + 4 * q + r, k = 16 * t4 + lc;
                sW1T[nn * 64 + ((((k >> 2) ^ (nn & 15)) << 2) | (k & 3))] = w1s[t4][r];
            }
        // Zbar partials
        float z2[4];
#pragma unroll
        for (int r = 0; r < 4; r++) { z2[r] = zba[r] + b1c; s1[r] = z2[r]; s2[r] = z2[r] * z2[r]; }
#pragma unroll
        for (int o = 1; o < 16; o <<= 1)
#pragma unroll
            for (int r = 0; r < 4; r++) { s1[r] += __shfl_xor(s1[r], o); s2[r] += __shfl_xor(s2[r], o); }
        if (lc == 0)
#pragma unroll
            for (int r = 0; r < 4; r++) {
                sRedC[(4 * q + r) * 8 + w] = s1[r];
                sRedC[(4 * q + r) * 8 + 4 + w] = s2[r];
            }
        __syncthreads();   // F

        // out = xq + LN(Zbar)
#pragma unroll
        for (int r = 0; r < 4; r++) {
            const float4 a = *(const float4*)&sRedC[(4 * q + r) * 8];
            const float4 b = *(const float4*)&sRedC[(4 * q + r) * 8 + 4];
            const float m1 = (a.x + a.y + a.z + a.w) * (1.0f / 64.0f);
            const float rr = rsqrtf((b.x + b.y + b.z + b.w) * (1.0f / 64.0f) - m1 * m1 + EPS_);
            const int row = 4 * q + r;
            xv_g[n * 1024 + row * 64 + col] =
                xqR[r] + gamC * ((z2[r] - m1) * rr) + betC;
        }
        clr = nlr;
    }
}

// ======================================================================
// post-norm: gather (B,NH,L,HD) -> LN over C=2048 -> fp32 (B,L,C)
// ======================================================================
__global__ __launch_bounds__(256)
void postln_kernel(const float* __restrict__ Ob, const float* __restrict__ pnw,
                   const float* __restrict__ pnb, float* __restrict__ XN)
{
    const int m = blockIdx.x;
    const int b = m >> 11, l = m & 2047;
    const int t = threadIdx.x;
    float v[8];
    float s1 = 0.0f, s2 = 0.0f;
    const float* bas = Ob + (size_t)b * NHEADS * L_SEQ * HDIM + (size_t)l * HDIM;
#pragma unroll
    for (int j = 0; j < 8; j++) {
        const int c = t + j * 256;
        const int hh = c >> 6, d = c & 63;
        const float x = bas[(size_t)hh * (L_SEQ * HDIM) + d];
        v[j] = x; s1 += x; s2 += x * x;
    }
#pragma unroll
    for (int o = 1; o < 64; o <<= 1) { s1 += __shfl_xor(s1, o); s2 += __shfl_xor(s2, o); }
    __shared__ float r1[4], r2[4];
    const int w = t >> 6;
    if ((t & 63) == 0) { r1[w] = s1; r2[w] = s2; }
    __syncthreads();
    s1 = r1[0] + r1[1] + r1[2] + r1[3];
    s2 = r2[0] + r2[1] + r2[2] + r2[3];
    const float mu = s1 * (1.0f / 2048.0f);
    const float var = s2 * (1.0f / 2048.0f) - mu * mu;
    const float rstd = rsqrtf(var + EPS_);
    float* o = XN + (size_t)m * C_DIM;
#pragma unroll
    for (int j = 0; j < 8; j++) {
        const int c = t + j * 256;
        o[c] = (v[j] - mu) * rstd * pnw[c] + pnb[c];
    }
}

// ======================================================================
extern "C" void kernel_launch(void* const* d_in, const int* in_sizes, int n_in,
                              void* d_out, int out_size, void* d_ws, size_t ws_size,
                              hipStream_t stream)
{
    (void)in_sizes; (void)n_in; (void)out_size; (void)ws_size;
    const float* hidden  = (const float*)d_in[0];
    const float* Wq      = (const float*)d_in[2];
    const float* Wk      = (const float*)d_in[3];
    const float* Wv      = (const float*)d_in[4];
    const float* Wo      = (const float*)d_in[5];
    const float* W1      = (const float*)d_in[6];
    const float* b1      = (const float*)d_in[7];
    const float* wlr     = (const float*)d_in[8];
    const float* lr_bias = (const float*)d_in[9];
    const float* lt      = (const float*)d_in[10];
    const float* lnw     = (const float*)d_in[11];
    const float* lnb     = (const float*)d_in[12];
    const float* pnw     = (const float*)d_in[13];
    const float* pnb     = (const float*)d_in[14];

    const size_t TEN = (size_t)B_DIM * NHEADS * L_SEQ * HDIM;  // 16777216
    float* XQ  = (float*)d_ws;
    float* XK  = XQ + TEN;
    float* XVo = XK + TEN;
    float* LRS = XVo + TEN;
    const dim3 blk(256);

    _Float16* BThi = (_Float16*)d_out;
    _Float16* BTlo = BThi + (size_t)C_DIM * C_DIM;

    lr_kernel<<<dim3(B_DIM * L_SEQ), blk, 0, stream>>>(hidden, wlr, lr_bias, LRS);

    const float* Wmats[3] = {Wq, Wk, Wv};
    float* outs[3] = {XQ, XK, XVo};
    for (int p = 0; p < 3; p++) {
        wtrans_kernel<<<dim3(64, 64), blk, 0, stream>>>(Wmats[p], BThi, BTlo, C_DIM);
        gemm_af32<<<dim3(16, 64), blk, 0, stream>>>(hidden, BThi, BTlo,
                                                    outs[p], 0, (p < 2) ? 1 : 0);
    }
    scan_v8<<<dim3(B_DIM * NHEADS), blk, 0, stream>>>(XQ, XK, XVo, LRS,
                                                      W1, b1, lt, lnw, lnb);
    float* XN = XQ;
    _Float16* WThi = (_Float16*)XK;
    _Float16* WTlo = WThi + (size_t)OUT_DIM * C_DIM;
    postln_kernel<<<dim3(B_DIM * L_SEQ), blk, 0, stream>>>(XVo, pnw, pnb, XN);
    wtrans_kernel<<<dim3(24, 64), blk, 0, stream>>>(Wo, WThi, WTlo, OUT_DIM);
    gemm_af32<<<dim3(6, 64), blk, 0, stream>>>(XN, WThi, WTlo,
                                               (float*)d_out, 1, 0);
}